// Round 11
// baseline (283.698 us; speedup 1.0000x reference)
//
#include <hip/hip_runtime.h>

// ---------------------------------------------------------------------------
// SgpiSTFT: Hermitian iFFT (as GEMM vs fixed cos/sin matrix) + window + 4-tap
// overlap-add + flip/transpose, fused.
//
// Round-11: AMPLIFIED PHASE ABLATION. R10's ablation was truncated by 41us
// fill dispatches in the top-5 table. This round amplifies each phase above
// the fill floor so all three land in the table:
//   gemm_ola<1,6>: 6x stage (batch rotated per rep; loads kept live)
//   gemm_ola<2,4>: stage + 4x K-loop (memory clobber per rep)
//   gemm_ola<0,4>: stage + K-loop + 4x IDEMPOTENT epilogue (correct output)
// Solve S,C,E; R12 attacks the fattest phase. Suspicion from R10: VGPR=36
// means the compiler serialized the K-loop (no a[4]/cb/nb live) -> C ~18us.
// ---------------------------------------------------------------------------

typedef __attribute__((ext_vector_type(8))) short short8;
typedef __attribute__((ext_vector_type(8))) __bf16 bf16x8;
typedef __attribute__((ext_vector_type(4))) float floatx4;

__device__ inline short f2bf(float f) {
  unsigned u = __builtin_bit_cast(unsigned, f);
  u = (u + 0x7fffu + ((u >> 16) & 1u)) >> 16;
  return (short)(unsigned short)u;
}

#define PI_OVER_256 0.01227184630308513f

// M matrix in MFMA fragment order (validated R3/R5/R9):
//   frag idx = (Jtile*16 + s)*64 + lane ; lane holds row j = Jtile*16+(lane&15),
//   kappa = s*32 + (lane>>4)*8 + e, e=0..7 (one short8 per lane).
//   kappa < 256: gk = 2*kappa (even);  kappa >= 256: gk = 2*(kappa-256)+1 (odd)
//   M[j][gk] = (gk==0) ? 1 : (gk<256 ? 2cos(2pi j gk/512) : 2sin(2pi j (gk-256)/512))
__global__ void build_m(short* __restrict__ M) {
  int idx = blockIdx.x * blockDim.x + threadIdx.x;  // [0, 16*16*64)
  int ntile = idx >> 10;
  int s = (idx >> 6) & 15;
  int lane = idx & 63;
  int n = ntile * 16 + (lane & 15);
  int kb = lane >> 4;
  short8 v;
#pragma unroll
  for (int e = 0; e < 8; e++) {
    int kap = s * 32 + kb * 8 + e;
    int gk = 2 * (kap & 255) + (kap >> 8);
    float val;
    if (gk == 0) {
      val = 1.0f;
    } else if (gk < 256) {
      int m = (n * gk) & 511;
      val = 2.0f * __cosf((float)m * PI_OVER_256);
    } else {
      int m = (n * (gk - 256)) & 511;
      val = 2.0f * __sinf((float)m * PI_OVER_256);
    }
    v[e] = f2bf(val);
  }
  ((short8*)M)[idx] = v;
}

// R5 structure (measured 41-46.5us): 1024 threads / 16 waves, 64-col tile,
// grid 67x8. Wave w owns j-tile J=w.
// MODE 0: stage + K-loop + REP x idempotent epilogue (CORRECT output).
// MODE 1: REP x stage (batch rotated), loads kept live, one LDS write.
// MODE 2: stage + REP x K-loop (memory clobber per rep), acc dumped.
template <int MODE, int REP>
__global__ __launch_bounds__(1024, 4) void gemm_ola(
    const float* __restrict__ in, const float* __restrict__ win,
    const short* __restrict__ M, float* __restrict__ out,
    float* __restrict__ dump) {
  __shared__ short ldsX[64 * 512];  // 64 KiB

  const int tid = threadIdx.x;
  const int b = blockIdx.y;
  const int tile = blockIdx.x;
  const int c0 = 60 * tile - 4;

  const int cbase = 4 * (tid & 15);      // 4 consecutive cols
  const int kap0 = (tid >> 4) * 8;       // 8 consecutive kappa, 0..504
  const int gc = c0 + cbase;
  const bool ok = (gc >= 0 && gc <= 3996);

  // ---- PHASE 1: stage X (dwordx4 global loads + register transpose) ----
  if (MODE == 1) {
    floatx4 a4 = {0.f, 0.f, 0.f, 0.f};
    floatx4 f[8];
#pragma unroll 1
    for (int r = 0; r < REP; ++r) {
      const float* src = in + (size_t)((b + r) & 7) * 2056000 + gc;
      if (ok) {
#pragma unroll
        for (int j = 0; j < 8; j++) {
          int kap = kap0 + j;
          int gk = 2 * (kap & 255) + (kap >> 8);
          int row = (gk < 256) ? gk : gk + 1;
          f[j] = *(const floatx4*)(src + (size_t)row * 4000);
        }
      } else {
#pragma unroll
        for (int j = 0; j < 8; j++) f[j] = floatx4{0.f, 0.f, 0.f, 0.f};
      }
#pragma unroll
      for (int j = 0; j < 8; j++) a4 += f[j];  // keeps every rep's loads live
      __syncthreads();                          // pace reps (memory fence)
    }
    // one real cvt+LDS write (keeps that path in the measurement once)
    const int g = kap0 >> 3;
#pragma unroll
    for (int cc = 0; cc < 4; cc++) {
      short8 v;
#pragma unroll
      for (int j = 0; j < 8; j++) v[j] = f2bf(f[j][cc]);
      const int col = cbase + cc;
      *(short8*)&ldsX[col * 512 + ((g ^ (col & 7)) << 3)] = v;
    }
    if (a4[0] == 123456.75f) dump[tid] = a4[1];  // never true at runtime
    return;
  }

  // real single stage (modes 0 and 2)
  {
    const float* src = in + (size_t)b * 2056000 + gc;
    floatx4 f[8];
    if (ok) {
#pragma unroll
      for (int j = 0; j < 8; j++) {
        int kap = kap0 + j;
        int gk = 2 * (kap & 255) + (kap >> 8);
        int row = (gk < 256) ? gk : gk + 1;  // imag rows start at 257
        f[j] = *(const floatx4*)(src + (size_t)row * 4000);
      }
    } else {
#pragma unroll
      for (int j = 0; j < 8; j++) f[j] = floatx4{0.f, 0.f, 0.f, 0.f};
    }
    const int g = kap0 >> 3;
#pragma unroll
    for (int cc = 0; cc < 4; cc++) {
      short8 v;
#pragma unroll
      for (int j = 0; j < 8; j++) v[j] = f2bf(f[j][cc]);
      const int col = cbase + cc;
      *(short8*)&ldsX[col * 512 + ((g ^ (col & 7)) << 3)] = v;
    }
  }
  __syncthreads();

  const int w = tid >> 6;    // wave id == j-tile J
  const int lane = tid & 63;
  const int c = lane & 15;   // MFMA spatial index within 16-tile
  const int rg = lane >> 4;  // k-block; also C row-group

  // ---- PHASE 2: MFMA main loop (REP x for MODE 2) ----
  floatx4 accE[4] = {};
  floatx4 accO[4] = {};
  const short8* Mf = (const short8*)M;
  const int CREP = (MODE == 2) ? REP : 1;

#pragma unroll 1
  for (int r = 0; r < CREP; ++r) {
    if (MODE == 2) asm volatile("" ::: "memory");  // force LDS/M re-reads
    bf16x8 cb = __builtin_bit_cast(bf16x8, Mf[(w * 16 + 0) * 64 + lane]);
#pragma unroll
    for (int s = 0; s < 16; s++) {
      bf16x8 nb;
      if (s < 15) {
        nb = __builtin_bit_cast(bf16x8, Mf[(w * 16 + s + 1) * 64 + lane]);
      }
      const int g = 4 * s + rg;
      bf16x8 a[4];
#pragma unroll
      for (int q = 0; q < 4; q++) {
        const int col = 16 * q + c;
        a[q] = __builtin_bit_cast(
            bf16x8, *(const short8*)&ldsX[col * 512 + ((g ^ (c & 7)) << 3)]);
      }
      if (s < 8) {
#pragma unroll
        for (int q = 0; q < 4; q++)
          accE[q] = __builtin_amdgcn_mfma_f32_16x16x32_bf16(a[q], cb, accE[q], 0, 0, 0);
      } else {
#pragma unroll
        for (int q = 0; q < 4; q++)
          accO[q] = __builtin_amdgcn_mfma_f32_16x16x32_bf16(a[q], cb, accO[q], 0, 0, 0);
      }
      if (s < 15) cb = nb;
    }
  }

  if (MODE == 2) {  // keep acc live, skip epilogue
    floatx4 sum = accE[0];
#pragma unroll
    for (int q = 0; q < 4; q++) {
      if (q) sum += accE[q];
      sum += accO[q];
    }
    const size_t bi = (size_t)(b * 67 + tile) * 1024 + tid;
    *(floatx4*)&dump[bi * 4] = sum;
    return;
  }

  // ---- PHASE 3: OLA epilogue, REP x idempotent (validated R5 math) ----
  // C layout: col (lane&15) = j within j-tile; row (rg*4+p) = local t offset.
  // Tap t-d = reg p-d; p-d<0 pulls reg p-d+4 from the row-group below
  // (lane-16, same q-tile) or, for rg==0, from rg=3 of tile q-1 (lane+48).
  // q==0 && rg==0 edge rows are L<4 -> masked.
#pragma unroll 1
  for (int r = 0; r < REP; ++r) {
    // opaque refresh: prevents hoisting the rep body (values are unchanged,
    // so the REP stores write identical data -> output stays correct)
#pragma unroll
    for (int q = 0; q < 4; q++) {
      asm volatile("" : "+v"(accE[q]), "+v"(accO[q]));
    }
    asm volatile("" ::: "memory");

    const int j = 16 * w + c;
    const float wv0 = 256.0f * win[768 + j];
    const float wv1 = 256.0f * win[512 + j];
    const float wv2 = 256.0f * win[256 + j];
    const float wv3 = 256.0f * win[j];

    floatx4 Y[4], Yh[4];
#pragma unroll
    for (int q = 0; q < 4; q++) {
      Y[q] = accE[q] + accO[q];
      Yh[q] = accE[q] - accO[q];
    }

#pragma unroll
    for (int q = 0; q < 4; q++) {
      const int qm = (q > 0) ? q - 1 : 0;  // q==0 edge is masked (L<4)
      float yb[4], yhb[4];
#pragma unroll
      for (int p = 1; p < 4; p++) {
        float ia = __shfl(Y[q][p], lane - 16, 64);
        float pa = __shfl(Y[qm][p], lane + 48, 64);
        yb[p] = (rg > 0) ? ia : pa;
      }
#pragma unroll
      for (int p = 2; p < 4; p++) {
        float ia = __shfl(Yh[q][p], lane - 16, 64);
        float pa = __shfl(Yh[qm][p], lane + 48, 64);
        yhb[p] = (rg > 0) ? ia : pa;
      }
      floatx4 v;
#pragma unroll
      for (int p = 0; p < 4; p++) {
        float t1 = (p >= 1) ? Y[q][p - 1] : yb[3];
        float t2 = (p >= 2) ? Yh[q][p - 2] : yhb[p + 2];
        float t3 = (p >= 3) ? Y[q][p - 3] : yb[p + 1];
        v[p] = wv0 * Yh[q][p] + wv1 * t1 + wv2 * t2 + wv3 * t3;
      }
#pragma unroll
      for (int p = 0; p < 4; p++) {
        const int L = 16 * q + 4 * rg + p;
        const int t = c0 + L;
        if (L >= 4 && t <= 3998) {
          out[((size_t)b * 3999 + t) * 256 + (255 - j)] = v[p];
        }
      }
    }
  }
}

extern "C" void kernel_launch(void* const* d_in, const int* in_sizes, int n_in,
                              void* d_out, int out_size, void* d_ws, size_t ws_size,
                              hipStream_t stream) {
  const float* in = (const float*)d_in[0];   // (8, 514, 4000) fp32
  const float* win = (const float*)d_in[1];  // (1024,) fp32
  float* out = (float*)d_out;                // (8, 3999*256) fp32
  short* M = (short*)d_ws;                   // 256 KiB bf16 coefficient matrix

  hipLaunchKernelGGL(build_m, dim3(64), dim3(256), 0, stream, M);

  float* dump = (float*)((char*)d_ws + ((size_t)32 << 20));
  if (ws_size >= ((size_t)48 << 20)) {
    // diagnostics (amplified so they clear the ~41us fill floor in top-5)
    hipLaunchKernelGGL((gemm_ola<1, 6>), dim3(67, 8), dim3(1024), 0, stream,
                       in, win, M, out, dump);
    hipLaunchKernelGGL((gemm_ola<2, 4>), dim3(67, 8), dim3(1024), 0, stream,
                       in, win, M, out, dump);
  }
  // production (correct output; epilogue repeated idempotently = E probe)
  hipLaunchKernelGGL((gemm_ola<0, 4>), dim3(67, 8), dim3(1024), 0, stream,
                     in, win, M, out, dump);
}

// Round 12
// 121.011 us; speedup vs baseline: 2.3444x; 2.3444x over previous
//
#include <hip/hip_runtime.h>

// ---------------------------------------------------------------------------
// SgpiSTFT: Hermitian iFFT (as GEMM vs fixed cos/sin matrix) + window + 4-tap
// overlap-add + flip/transpose, fused.
//
//   y[n,t] = Re(c0) + 2*sum_{k=1..255}( Re_k cos(2pi n k/512) + Im_k sin(...) )
//   out[b, t*256 + (255-j)] = 256*( y[256+j,t]  *win[768+j]
//                                  + y[j,  t-1] *win[512+j]
//                                  + y[256+j,t-2]*win[256+j]
//                                  + y[j,  t-3] *win[j] )
// E/O split: Y=E+O (y[j]), Yh=E-O (y[256+j]).
//
// Round-12: M-out-of-K-loop. R11 ablation solved the phase budget:
// S(stage)=15us @3.2TB/s, C(K-loop)=20-24us, E(epilogue)=2-6us, serial sum
// = 41-45us observed. C is 2-3x its LDS floor: the in-loop global M loads
// (200cy L2 latency, depth-1) + register starvation (VGPR=36) serialize it.
// This round: preload the wave's M slice into registers in two 8-step halves
// (32 VGPR each; half-0 issued before the staging loads so both streams fly
// together), K-loop = pure LDS+MFMA with explicit a_cur/a_nxt double buffer.
// Frame (grid 67x8, 1024thr/16 waves, staging, M layout, epilogue) = R5,
// validated & measured 44-46us.
// ---------------------------------------------------------------------------

typedef __attribute__((ext_vector_type(8))) short short8;
typedef __attribute__((ext_vector_type(8))) __bf16 bf16x8;
typedef __attribute__((ext_vector_type(4))) float floatx4;

__device__ inline short f2bf(float f) {
  unsigned u = __builtin_bit_cast(unsigned, f);
  u = (u + 0x7fffu + ((u >> 16) & 1u)) >> 16;
  return (short)(unsigned short)u;
}

#define PI_OVER_256 0.01227184630308513f

// M matrix in MFMA fragment order (validated R3/R5/R9):
//   frag idx = (Jtile*16 + s)*64 + lane ; lane holds row j = Jtile*16+(lane&15),
//   kappa = s*32 + (lane>>4)*8 + e, e=0..7 (one short8 per lane).
//   kappa < 256: gk = 2*kappa (even);  kappa >= 256: gk = 2*(kappa-256)+1 (odd)
//   M[j][gk] = (gk==0) ? 1 : (gk<256 ? 2cos(2pi j gk/512) : 2sin(2pi j (gk-256)/512))
__global__ void build_m(short* __restrict__ M) {
  int idx = blockIdx.x * blockDim.x + threadIdx.x;  // [0, 16*16*64)
  int ntile = idx >> 10;
  int s = (idx >> 6) & 15;
  int lane = idx & 63;
  int n = ntile * 16 + (lane & 15);
  int kb = lane >> 4;
  short8 v;
#pragma unroll
  for (int e = 0; e < 8; e++) {
    int kap = s * 32 + kb * 8 + e;
    int gk = 2 * (kap & 255) + (kap >> 8);
    float val;
    if (gk == 0) {
      val = 1.0f;
    } else if (gk < 256) {
      int m = (n * gk) & 511;
      val = 2.0f * __cosf((float)m * PI_OVER_256);
    } else {
      int m = (n * (gk - 256)) & 511;
      val = 2.0f * __sinf((float)m * PI_OVER_256);
    }
    v[e] = f2bf(val);
  }
  ((short8*)M)[idx] = v;
}

// Block: batch b, X columns [c0, c0+64), c0 = 60*tile - 4 (halo 4). Outputs
// local L in [4,64) -> t = c0+L, masked to t <= 3998. 1024 threads = 16
// waves; wave w owns j-tile J=w (j rows 16w..16w+15) for all 64 t-columns.
__global__ __launch_bounds__(1024, 4) void gemm_ola(
    const float* __restrict__ in, const float* __restrict__ win,
    const short* __restrict__ M, float* __restrict__ out) {
  // X tile, bf16, column-major [col][kappa], kappa groups of 8 XOR-swizzled
  // by (col&7) -> conflict-light b128 reads.
  __shared__ short ldsX[64 * 512];  // 64 KiB

  const int tid = threadIdx.x;
  const int b = blockIdx.y;
  const int tile = blockIdx.x;
  const int c0 = 60 * tile - 4;

  const int w = tid >> 6;    // wave id == j-tile J
  const int lane = tid & 63;
  const int c = lane & 15;   // MFMA spatial index within 16-tile
  const int rg = lane >> 4;  // k-block; also C row-group

  // Per-wave M slice base: fragment (w*16 + s)*64 + lane.
  const short8* Mw = (const short8*)M + (size_t)(w * 16) * 64 + lane;

  // ---- issue M half-0 loads FIRST (L2-hot; fly alongside staging loads) --
  bf16x8 mreg[8];
#pragma unroll
  for (int i = 0; i < 8; i++)
    mreg[i] = __builtin_bit_cast(bf16x8, Mw[i * 64]);

  // ---- stage X: dwordx4 global loads + register transpose -> bf16 LDS ----
  {
    const int cbase = 4 * (tid & 15);      // 4 consecutive cols
    const int kap0 = (tid >> 4) * 8;       // 8 consecutive kappa, 0..504
    const int gc = c0 + cbase;
    const bool ok = (gc >= 0 && gc <= 3996);
    const float* src = in + (size_t)b * 2056000 + gc;
    floatx4 f[8];
    if (ok) {
#pragma unroll
      for (int j = 0; j < 8; j++) {
        int kap = kap0 + j;
        int gk = 2 * (kap & 255) + (kap >> 8);
        int row = (gk < 256) ? gk : gk + 1;  // imag rows start at 257
        f[j] = *(const floatx4*)(src + (size_t)row * 4000);
      }
    } else {
#pragma unroll
      for (int j = 0; j < 8; j++) f[j] = floatx4{0.f, 0.f, 0.f, 0.f};
    }
    const int g = kap0 >> 3;  // kappa-group, == tid>>4
#pragma unroll
    for (int cc = 0; cc < 4; cc++) {
      short8 v;
#pragma unroll
      for (int j = 0; j < 8; j++) v[j] = f2bf(f[j][cc]);
      const int col = cbase + cc;
      *(short8*)&ldsX[col * 512 + ((g ^ (col & 7)) << 3)] = v;
    }
  }
  __syncthreads();

  // ---- K-loop: pure LDS + MFMA, explicit a double-buffer ----
  floatx4 accE[4] = {};
  floatx4 accO[4] = {};

#define LDSA(Q, G)                                                         \
  __builtin_bit_cast(bf16x8, *(const short8*)&ldsX[(16 * (Q) + c) * 512 +  \
                                                   (((G) ^ (c & 7)) << 3)])

#define HALF(SBASE, ACC)                                                   \
  {                                                                        \
    bf16x8 acur[4], anxt[4];                                               \
    _Pragma("unroll") for (int q = 0; q < 4; q++)                          \
        acur[q] = LDSA(q, 4 * (SBASE) + rg);                               \
    _Pragma("unroll") for (int si = 0; si < 8; si++) {                     \
      if (si < 7) {                                                        \
        const int gn = 4 * ((SBASE) + si + 1) + rg;                        \
        _Pragma("unroll") for (int q = 0; q < 4; q++)                      \
            anxt[q] = LDSA(q, gn);                                         \
      }                                                                    \
      _Pragma("unroll") for (int q = 0; q < 4; q++)                        \
          ACC[q] = __builtin_amdgcn_mfma_f32_16x16x32_bf16(                \
              acur[q], mreg[si], ACC[q], 0, 0, 0);                         \
      if (si < 7) {                                                        \
        _Pragma("unroll") for (int q = 0; q < 4; q++) acur[q] = anxt[q];   \
      }                                                                    \
    }                                                                      \
  }

  // half 0: even-k (s = 0..7)
  HALF(0, accE);

  // reload M for half 1 (8 independent 16B loads, one drain)
#pragma unroll
  for (int i = 0; i < 8; i++)
    mreg[i] = __builtin_bit_cast(bf16x8, Mw[(8 + i) * 64]);

  // half 1: odd-k (s = 8..15)
  HALF(8, accO);

#undef HALF
#undef LDSA

  // ---- OLA epilogue (validated R5) ----
  // C layout: col (lane&15) = j within j-tile; row (rg*4+p) = local t offset.
  // Tap t-d = reg p-d; p-d<0 pulls reg p-d+4 from the row-group below
  // (lane-16, same q-tile) or, for rg==0, from rg=3 of tile q-1 (lane+48).
  // q==0 && rg==0 edge rows are L<4 -> masked.
  {
    const int j = 16 * w + c;
    const float wv0 = 256.0f * win[768 + j];
    const float wv1 = 256.0f * win[512 + j];
    const float wv2 = 256.0f * win[256 + j];
    const float wv3 = 256.0f * win[j];

    floatx4 Y[4], Yh[4];
#pragma unroll
    for (int q = 0; q < 4; q++) {
      Y[q] = accE[q] + accO[q];
      Yh[q] = accE[q] - accO[q];
    }

#pragma unroll
    for (int q = 0; q < 4; q++) {
      const int qm = (q > 0) ? q - 1 : 0;  // q==0 edge is masked (L<4)
      float yb[4], yhb[4];
#pragma unroll
      for (int p = 1; p < 4; p++) {
        float ia = __shfl(Y[q][p], lane - 16, 64);
        float pa = __shfl(Y[qm][p], lane + 48, 64);
        yb[p] = (rg > 0) ? ia : pa;
      }
#pragma unroll
      for (int p = 2; p < 4; p++) {
        float ia = __shfl(Yh[q][p], lane - 16, 64);
        float pa = __shfl(Yh[qm][p], lane + 48, 64);
        yhb[p] = (rg > 0) ? ia : pa;
      }
      floatx4 v;
#pragma unroll
      for (int p = 0; p < 4; p++) {
        float t1 = (p >= 1) ? Y[q][p - 1] : yb[3];
        float t2 = (p >= 2) ? Yh[q][p - 2] : yhb[p + 2];
        float t3 = (p >= 3) ? Y[q][p - 3] : yb[p + 1];
        v[p] = wv0 * Yh[q][p] + wv1 * t1 + wv2 * t2 + wv3 * t3;
      }
#pragma unroll
      for (int p = 0; p < 4; p++) {
        const int L = 16 * q + 4 * rg + p;
        const int t = c0 + L;
        if (L >= 4 && t <= 3998) {
          out[((size_t)b * 3999 + t) * 256 + (255 - j)] = v[p];
        }
      }
    }
  }
}

extern "C" void kernel_launch(void* const* d_in, const int* in_sizes, int n_in,
                              void* d_out, int out_size, void* d_ws, size_t ws_size,
                              hipStream_t stream) {
  const float* in = (const float*)d_in[0];   // (8, 514, 4000) fp32
  const float* win = (const float*)d_in[1];  // (1024,) fp32
  float* out = (float*)d_out;                // (8, 3999*256) fp32
  short* M = (short*)d_ws;                   // 256 KiB bf16 coefficient matrix

  hipLaunchKernelGGL(build_m, dim3(64), dim3(256), 0, stream, M);
  hipLaunchKernelGGL(gemm_ola, dim3(67, 8), dim3(1024), 0, stream, in, win, M, out);
}

// Round 13
// 120.533 us; speedup vs baseline: 2.3537x; 1.0040x over previous
//
#include <hip/hip_runtime.h>

// ---------------------------------------------------------------------------
// SgpiSTFT: Hermitian iFFT (as GEMM vs fixed cos/sin matrix) + window + 4-tap
// overlap-add + flip/transpose, fused.
//
//   y[n,t] = Re(c0) + 2*sum_{k=1..255}( Re_k cos(2pi n k/512) + Im_k sin(...) )
//   out[b, t*256 + (255-j)] = 256*( y[256+j,t]  *win[768+j]
//                                  + y[j,  t-1] *win[512+j]
//                                  + y[256+j,t-2]*win[256+j]
//                                  + y[j,  t-3] *win[j] )
// E/O split: Y=E+O (y[j]), Yh=E-O (y[256+j]).
//
// Round-13: producer/consumer wave specialization. Seven structural probes
// (R0/R3/R5/R6/R8/R12) all 42-49us; ablation budget S=15 C=20-24 E=2-6us,
// serial sum = observed. Diagnosis: co-resident blocks run phase-locked
// (identical code/durations) -> HBM and LDS/MFMA never concurrent (m233
// 2-phase stall); R8's chunking kept phases co-scheduled; R0's 4-deep
// residency proves multi-block doesn't desync. This round splits the block:
// waves 8-15 = producers (stream X chunk ch+1: fp32 pair loads -> bf16 ->
// 16KiB ping-pong LDS buffers), waves 0-7 = consumers (K-loop on chunk ch,
// R3's VALIDATED 2-j-tiles/wave layout + epilogue). One barrier per chunk,
// uniform control flow. HBM and LDS/MFMA now busy SIMULTANEOUSLY between
// barriers by construction. LDS 32KiB; VGPR ~106 -> 16 waves/CU (1 block).
// ---------------------------------------------------------------------------

typedef __attribute__((ext_vector_type(8))) short short8;
typedef __attribute__((ext_vector_type(8))) __bf16 bf16x8;
typedef __attribute__((ext_vector_type(4))) float floatx4;
typedef __attribute__((ext_vector_type(2))) float floatx2;

__device__ inline short f2bf(float f) {
  unsigned u = __builtin_bit_cast(unsigned, f);
  u = (u + 0x7fffu + ((u >> 16) & 1u)) >> 16;
  return (short)(unsigned short)u;
}

#define PI_OVER_256 0.01227184630308513f

// M matrix in MFMA fragment order (validated R3/R5/R9):
//   frag idx = (Jtile*16 + s)*64 + lane ; lane holds row j = Jtile*16+(lane&15),
//   kappa = s*32 + (lane>>4)*8 + e, e=0..7 (one short8 per lane).
//   kappa < 256: gk = 2*kappa (even);  kappa >= 256: gk = 2*(kappa-256)+1 (odd)
//   M[j][gk] = (gk==0) ? 1 : (gk<256 ? 2cos(2pi j gk/512) : 2sin(2pi j (gk-256)/512))
__global__ void build_m(short* __restrict__ M) {
  int idx = blockIdx.x * blockDim.x + threadIdx.x;  // [0, 16*16*64)
  int ntile = idx >> 10;
  int s = (idx >> 6) & 15;
  int lane = idx & 63;
  int n = ntile * 16 + (lane & 15);
  int kb = lane >> 4;
  short8 v;
#pragma unroll
  for (int e = 0; e < 8; e++) {
    int kap = s * 32 + kb * 8 + e;
    int gk = 2 * (kap & 255) + (kap >> 8);
    float val;
    if (gk == 0) {
      val = 1.0f;
    } else if (gk < 256) {
      int m = (n * gk) & 511;
      val = 2.0f * __cosf((float)m * PI_OVER_256);
    } else {
      int m = (n * (gk - 256)) & 511;
      val = 2.0f * __sinf((float)m * PI_OVER_256);
    }
    v[e] = f2bf(val);
  }
  ((short8*)M)[idx] = v;
}

// Block: batch b, X columns [c0, c0+64), c0 = 60*tile - 4 (halo 4). Outputs
// local L in [4,64) -> t = c0+L, masked to t <= 3998.
// 1024 threads: waves 0-7 consumers (wave w owns j-tiles {2w,2w+1}, all 64
// t-cols), waves 8-15 producers (stream kappa chunks of 128 into ping-pong
// bf16 LDS buffers). kappa decomposition: global kappa = ch*128 + (4*si+rg)*8
// + e with s = 4*ch+si -> local group g_l = 4*si+rg in [0,16).
__global__ __launch_bounds__(1024, 4) void gemm_ola(
    const float* __restrict__ in, const float* __restrict__ win,
    const short* __restrict__ M, float* __restrict__ out) {
  // ping-pong chunk buffers: [buf][col][kappa_local], XOR-swizzled groups.
  __shared__ short ldsB[2][64 * 128];  // 2 x 16 KiB

  const int tid = threadIdx.x;
  const int b = blockIdx.y;
  const int tile = blockIdx.x;
  const int c0 = 60 * tile - 4;

  const bool producer = (tid >= 512);

  // producer geometry: 512 threads cover 32 col-pairs x 16 kappa-groups
  const int pp = tid & 511;
  const int cp = pp & 31;       // col pair -> cols {2cp, 2cp+1}
  const int pkg = pp >> 5;      // local kappa-group 0..15
  const int pgc = c0 + 2 * cp;
  const bool pok = (pgc >= 0 && pgc <= 3998);
  const float* psrc = in + (size_t)b * 2056000 + pgc;

  // consumer geometry (R3-validated)
  const int w = tid >> 6;       // 0..7 for consumers
  const int lane = tid & 63;
  const int c = lane & 15;      // MFMA spatial index within 16-tile
  const int rg = lane >> 4;     // k-block; also C row-group
  const short8* Mf = (const short8*)M;
  const int J0 = 2 * w, J1 = 2 * w + 1;

  // STAGE(CH): load chunk CH (fp32 pairs), convert, write ldsB[CH&1].
#define STAGE(CH)                                                           \
  {                                                                         \
    floatx2 f[8];                                                           \
    if (pok) {                                                              \
      _Pragma("unroll") for (int e = 0; e < 8; e++) {                       \
        const int kap = (CH) * 128 + pkg * 8 + e;                           \
        const int gk = 2 * (kap & 255) + (kap >> 8);                        \
        const int row = (gk < 256) ? gk : gk + 1;                           \
        f[e] = *(const floatx2*)(psrc + (size_t)row * 4000);                \
      }                                                                     \
    } else {                                                                \
      _Pragma("unroll") for (int e = 0; e < 8; e++) f[e] = floatx2{0.f, 0.f}; \
    }                                                                       \
    _Pragma("unroll") for (int cc = 0; cc < 2; cc++) {                      \
      short8 v;                                                             \
      _Pragma("unroll") for (int e = 0; e < 8; e++) v[e] = f2bf(f[e][cc]);  \
      const int col = 2 * cp + cc;                                          \
      *(short8*)&ldsB[(CH) & 1][col * 128 + ((pkg ^ (col & 7)) << 3)] = v;  \
    }                                                                       \
  }

  // acc[q][jt]: q = t-tile (4 x 16 cols), jt = j-tile; E = even-k, O = odd-k
  floatx4 accE[4][2] = {};
  floatx4 accO[4][2] = {};
  bf16x8 cb0, cb1;

  // ---- prologue: producers stage chunk 0; consumers preload M step 0 ----
  if (producer) {
    STAGE(0);
  } else {
    cb0 = __builtin_bit_cast(bf16x8, Mf[(J0 * 16 + 0) * 64 + lane]);
    cb1 = __builtin_bit_cast(bf16x8, Mf[(J1 * 16 + 0) * 64 + lane]);
  }
  __syncthreads();

#pragma unroll
  for (int ch = 0; ch < 4; ch++) {
    if (producer) {
      if (ch < 3) STAGE(ch + 1);  // writes ldsB[(ch+1)&1], disjoint from reads
    } else {
#pragma unroll
      for (int si = 0; si < 4; si++) {
        const int s = 4 * ch + si;
        bf16x8 nb0, nb1;
        if (s < 15) {
          nb0 = __builtin_bit_cast(bf16x8, Mf[(J0 * 16 + s + 1) * 64 + lane]);
          nb1 = __builtin_bit_cast(bf16x8, Mf[(J1 * 16 + s + 1) * 64 + lane]);
        }
        const int gl = 4 * si + rg;  // local kappa-group
        bf16x8 a[4];
#pragma unroll
        for (int q = 0; q < 4; q++) {
          const int col = 16 * q + c;
          a[q] = __builtin_bit_cast(
              bf16x8,
              *(const short8*)&ldsB[ch & 1][col * 128 + ((gl ^ (c & 7)) << 3)]);
        }
        if (s < 8) {
#pragma unroll
          for (int q = 0; q < 4; q++) {
            accE[q][0] = __builtin_amdgcn_mfma_f32_16x16x32_bf16(a[q], cb0, accE[q][0], 0, 0, 0);
            accE[q][1] = __builtin_amdgcn_mfma_f32_16x16x32_bf16(a[q], cb1, accE[q][1], 0, 0, 0);
          }
        } else {
#pragma unroll
          for (int q = 0; q < 4; q++) {
            accO[q][0] = __builtin_amdgcn_mfma_f32_16x16x32_bf16(a[q], cb0, accO[q][0], 0, 0, 0);
            accO[q][1] = __builtin_amdgcn_mfma_f32_16x16x32_bf16(a[q], cb1, accO[q][1], 0, 0, 0);
          }
        }
        if (s < 15) { cb0 = nb0; cb1 = nb1; }
      }
    }
    __syncthreads();  // chunk handoff (hit by all 16 waves, 4x)
  }
#undef STAGE

  if (producer) return;  // no barriers past this point

  // ---- OLA epilogue (validated R3/R6) ----
  // C layout: col (lane&15) = j within j-tile; row (rg*4+p) = local t offset.
  // Tap t-d = reg p-d; p-d<0 pulls reg p-d+4 from the row-group below
  // (lane-16, same q-tile) or, for rg==0, from rg=3 of tile q-1 (lane+48).
  // q==0 && rg==0 edge rows are L<4 -> masked.
#pragma unroll
  for (int jt = 0; jt < 2; jt++) {
    const int j = 16 * (2 * w + jt) + c;
    const float wv0 = 256.0f * win[768 + j];
    const float wv1 = 256.0f * win[512 + j];
    const float wv2 = 256.0f * win[256 + j];
    const float wv3 = 256.0f * win[j];

    floatx4 Y[4], Yh[4];
#pragma unroll
    for (int q = 0; q < 4; q++) {
      Y[q] = accE[q][jt] + accO[q][jt];
      Yh[q] = accE[q][jt] - accO[q][jt];
    }

#pragma unroll
    for (int q = 0; q < 4; q++) {
      const int qm = (q > 0) ? q - 1 : 0;  // q==0 edge is masked (L<4)
      float yb[4], yhb[4];
#pragma unroll
      for (int p = 1; p < 4; p++) {
        float ia = __shfl(Y[q][p], lane - 16, 64);
        float pa = __shfl(Y[qm][p], lane + 48, 64);
        yb[p] = (rg > 0) ? ia : pa;
      }
#pragma unroll
      for (int p = 2; p < 4; p++) {
        float ia = __shfl(Yh[q][p], lane - 16, 64);
        float pa = __shfl(Yh[qm][p], lane + 48, 64);
        yhb[p] = (rg > 0) ? ia : pa;
      }
      floatx4 v;
#pragma unroll
      for (int p = 0; p < 4; p++) {
        float t1 = (p >= 1) ? Y[q][p - 1] : yb[3];
        float t2 = (p >= 2) ? Yh[q][p - 2] : yhb[p + 2];
        float t3 = (p >= 3) ? Y[q][p - 3] : yb[p + 1];
        v[p] = wv0 * Yh[q][p] + wv1 * t1 + wv2 * t2 + wv3 * t3;
      }
#pragma unroll
      for (int p = 0; p < 4; p++) {
        const int L = 16 * q + 4 * rg + p;
        const int t = c0 + L;
        if (L >= 4 && t <= 3998) {
          out[((size_t)b * 3999 + t) * 256 + (255 - j)] = v[p];
        }
      }
    }
  }
}

extern "C" void kernel_launch(void* const* d_in, const int* in_sizes, int n_in,
                              void* d_out, int out_size, void* d_ws, size_t ws_size,
                              hipStream_t stream) {
  const float* in = (const float*)d_in[0];   // (8, 514, 4000) fp32
  const float* win = (const float*)d_in[1];  // (1024,) fp32
  float* out = (float*)d_out;                // (8, 3999*256) fp32
  short* M = (short*)d_ws;                   // 256 KiB bf16 coefficient matrix

  hipLaunchKernelGGL(build_m, dim3(64), dim3(256), 0, stream, M);
  hipLaunchKernelGGL(gemm_ola, dim3(67, 8), dim3(1024), 0, stream, in, win, M, out);
}